// Round 5
// baseline (167.263 us; speedup 1.0000x reference)
//
#include <hip/hip_runtime.h>
#include <hip/hip_cooperative_groups.h>

namespace cg = cooperative_groups;

// TreeCrfLoss single cooperative dispatch:
//   pot = sum_i U[i, tl[i]]  +  sum_{c>=1} E[c, tl[(c-1)/4], tl[c]]
//   out = z - pot,  z = logsumexp(beliefs[0, 0:16])
// Thread handles node pairs {n0, n0+1} (grid-stride); parent of n is (n-1)>>2.
// grid.sync() then block 0 reduces the per-block partials — counter-free,
// deterministic, no workspace state carried across calls.

#define NTHR 256
#define NBLK 1024   // 4 blocks/CU on 256 CUs; co-resident (low VGPR/LDS)

__device__ __forceinline__ float nt_load(const float* p) {
    return __builtin_nontemporal_load(p);
}

__global__ __launch_bounds__(NTHR) void tree_crf_coop(
    const float* __restrict__ U,        // [N,16]
    const float* __restrict__ E,        // [N,16,16]
    const float* __restrict__ beliefs,  // [N,16] (row 0 only)
    const int*   __restrict__ tl,       // [N]
    float* __restrict__ out,            // [1]
    float* __restrict__ partials,       // [NBLK] in ws
    int N)
{
    cg::grid_group grid = cg::this_grid();

    const int tid    = blockIdx.x * NTHR + threadIdx.x;
    const int stride = NBLK * NTHR;
    float acc = 0.0f;

    for (int n0 = tid << 1; n0 < N; n0 += stride << 1) {
        const int n1 = n0 + 1;
        if (n1 < N) {
            const int2 l2 = *reinterpret_cast<const int2*>(tl + n0);  // 8B aligned
            const int p1 = tl[n0 >> 2];                               // parent label of n1
            const int p0 = (n0 >= 1) ? tl[(n0 - 1) >> 2] : 0;         // parent label of n0

            const float u0 = nt_load(&U[((size_t)n0 << 4) + l2.x]);
            const float u1 = nt_load(&U[((size_t)n1 << 4) + l2.y]);
            const float e1 = nt_load(&E[((size_t)n1 << 8) + p1 * 16 + l2.y]);
            float e0 = 0.0f;
            if (n0 >= 1)
                e0 = nt_load(&E[((size_t)n0 << 8) + p0 * 16 + l2.x]);
            acc += (u0 + u1) + (e0 + e1);
        } else {                       // single tail node (N odd)
            const int l = tl[n0];
            acc += U[((size_t)n0 << 4) + l];
            if (n0 >= 1)
                acc += E[((size_t)n0 << 8) + tl[(n0 - 1) >> 2] * 16 + l];
        }
    }

    // wave (64-lane) + LDS block reduction
    #pragma unroll
    for (int off = 32; off > 0; off >>= 1)
        acc += __shfl_down(acc, off, 64);
    __shared__ float s[NTHR / 64];
    const int lane = threadIdx.x & 63;
    const int wave = threadIdx.x >> 6;
    if (lane == 0) s[wave] = acc;
    __syncthreads();
    if (threadIdx.x == 0) {
        float v = 0.0f;
        #pragma unroll
        for (int w = 0; w < NTHR / 64; ++w) v += s[w];
        __hip_atomic_store(&partials[blockIdx.x], v, __ATOMIC_RELAXED,
                           __HIP_MEMORY_SCOPE_AGENT);
    }

    grid.sync();   // device-wide barrier + memory visibility

    if (blockIdx.x == 0) {
        float a = 0.0f;
        for (int i = threadIdx.x; i < NBLK; i += NTHR)
            a += __hip_atomic_load(&partials[i], __ATOMIC_RELAXED,
                                   __HIP_MEMORY_SCOPE_AGENT);
        #pragma unroll
        for (int off = 32; off > 0; off >>= 1)
            a += __shfl_down(a, off, 64);
        if (lane == 0) s[wave] = a;
        __syncthreads();
        if (threadIdx.x == 0) {
            float pot = 0.0f;
            #pragma unroll
            for (int w = 0; w < NTHR / 64; ++w) pot += s[w];
            float m = beliefs[0];
            #pragma unroll
            for (int j = 1; j < 16; ++j) m = fmaxf(m, beliefs[j]);
            float se = 0.0f;
            #pragma unroll
            for (int j = 0; j < 16; ++j) se += __expf(beliefs[j] - m);
            const float z = m + __logf(se);
            out[0] = z - pot;   // -(pot - z)
        }
    }
}

extern "C" void kernel_launch(void* const* d_in, const int* in_sizes, int n_in,
                              void* d_out, int out_size, void* d_ws, size_t ws_size,
                              hipStream_t stream) {
    const float* U       = (const float*)d_in[0];
    const float* E       = (const float*)d_in[1];
    const float* beliefs = (const float*)d_in[2];
    const int*   tl      = (const int*)d_in[3];
    int N = in_sizes[3];

    float* partials = (float*)d_ws;   // NBLK floats, fully overwritten every call
    float* out      = (float*)d_out;

    void* args[] = { (void*)&U, (void*)&E, (void*)&beliefs, (void*)&tl,
                     (void*)&out, (void*)&partials, (void*)&N };
    hipLaunchCooperativeKernel((const void*)tree_crf_coop,
                               dim3(NBLK), dim3(NTHR), args, 0, stream);
}

// Round 6
// 21.391 us; speedup vs baseline: 7.8195x; 7.8195x over previous
//
#include <hip/hip_runtime.h>

// TreeCrfLoss, two-dispatch (proven structure, R1=21.4us), higher occupancy:
//   pot = sum_i U[i, tl[i]]  +  sum_{c>=1} E[c, tl[(c-1)/4], tl[c]]
//   out = z - pot,  z = logsumexp(beliefs[0, 0:16])
// Thread handles node pair {n0, n0+1}, n0 = 2*tid. Parent of n is (n-1)>>2.
// 977 blocks -> ~15 waves/CU for gather-latency hiding (R1 had only ~7.6).

#define NTHR 256

__device__ __forceinline__ float nt_load(const float* p) {
    return __builtin_nontemporal_load(p);
}

__global__ __launch_bounds__(NTHR) void tree_crf_partial(
    const float* __restrict__ U,      // [N,16]
    const float* __restrict__ E,      // [N,16,16]
    const int* __restrict__ tl,       // [N]
    float* __restrict__ partials,     // [gridDim.x]
    int N)
{
    const int tid = blockIdx.x * NTHR + threadIdx.x;
    const int n0  = tid << 1;
    float acc = 0.0f;

    if (n0 + 1 < N) {
        const int n1 = n0 + 1;
        const int2 l2 = *reinterpret_cast<const int2*>(tl + n0);   // 8B aligned
        const int p1 = tl[n0 >> 2];                                 // parent label of n1
        const int p0 = (n0 >= 1) ? tl[(n0 - 1) >> 2] : 0;           // parent label of n0

        const float u0 = nt_load(&U[((size_t)n0 << 4) + l2.x]);
        const float u1 = nt_load(&U[((size_t)n1 << 4) + l2.y]);
        const float e1 = nt_load(&E[((size_t)n1 << 8) + p1 * 16 + l2.y]);
        float e0 = 0.0f;
        if (n0 >= 1)
            e0 = nt_load(&E[((size_t)n0 << 8) + p0 * 16 + l2.x]);
        acc = (u0 + u1) + (e0 + e1);
    } else if (n0 < N) {                 // single tail node (N odd)
        const int l = tl[n0];
        acc = U[((size_t)n0 << 4) + l];
        if (n0 >= 1)
            acc += E[((size_t)n0 << 8) + tl[(n0 - 1) >> 2] * 16 + l];
    }

    // 64-lane wave reduction + LDS across waves
    #pragma unroll
    for (int off = 32; off > 0; off >>= 1)
        acc += __shfl_down(acc, off, 64);
    __shared__ float s[NTHR / 64];
    const int lane = threadIdx.x & 63;
    const int wave = threadIdx.x >> 6;
    if (lane == 0) s[wave] = acc;
    __syncthreads();
    if (threadIdx.x == 0) {
        float v = 0.0f;
        #pragma unroll
        for (int w = 0; w < NTHR / 64; ++w) v += s[w];
        partials[blockIdx.x] = v;
    }
}

__global__ __launch_bounds__(NTHR) void tree_crf_finalize(
    const float* __restrict__ beliefs,   // [N,16], only row 0 used
    const float* __restrict__ partials,  // [nb]
    float* __restrict__ out,
    int nb)
{
    float acc = 0.0f;
    for (int i = threadIdx.x; i < nb; i += NTHR)
        acc += partials[i];
    #pragma unroll
    for (int off = 32; off > 0; off >>= 1)
        acc += __shfl_down(acc, off, 64);
    __shared__ float s[NTHR / 64];
    const int lane = threadIdx.x & 63;
    const int wave = threadIdx.x >> 6;
    if (lane == 0) s[wave] = acc;
    __syncthreads();
    if (threadIdx.x == 0) {
        float pot = 0.0f;
        #pragma unroll
        for (int w = 0; w < NTHR / 64; ++w) pot += s[w];
        float m = beliefs[0];
        #pragma unroll
        for (int j = 1; j < 16; ++j) m = fmaxf(m, beliefs[j]);
        float se = 0.0f;
        #pragma unroll
        for (int j = 0; j < 16; ++j) se += __expf(beliefs[j] - m);
        const float z = m + __logf(se);
        out[0] = z - pot;   // -(pot - z)
    }
}

extern "C" void kernel_launch(void* const* d_in, const int* in_sizes, int n_in,
                              void* d_out, int out_size, void* d_ws, size_t ws_size,
                              hipStream_t stream) {
    const float* U       = (const float*)d_in[0];   // unary_potentials [N,16]
    const float* E       = (const float*)d_in[1];   // edge_potentials [N,16,16]
    const float* beliefs = (const float*)d_in[2];   // beliefs [N,16]
    const int*   tl      = (const int*)d_in[3];     // true_labels [N]
    const int N = in_sizes[3];

    const int threads_needed = (N + 1) >> 1;                 // 2 nodes/thread
    const int nb = (threads_needed + NTHR - 1) / NTHR;       // 977 for N=500000

    float* partials = (float*)d_ws;   // nb floats, fully overwritten each call
    float* out      = (float*)d_out;

    tree_crf_partial<<<nb, NTHR, 0, stream>>>(U, E, tl, partials, N);
    tree_crf_finalize<<<1, NTHR, 0, stream>>>(beliefs, partials, out, nb);
}